// Round 17
// baseline (278.486 us; speedup 1.0000x reference)
//
#include <hip/hip_runtime.h>

#define D 128

typedef short bfrag __attribute__((ext_vector_type(8)));      // 8 bf16 = 4 VGPRs
typedef float f32x4 __attribute__((ext_vector_type(4)));
typedef unsigned uint32;

// ---------------- bf16 split helpers ----------------
__device__ inline unsigned short bf16_rne(float x) {
    unsigned u = __float_as_uint(x);
    return (unsigned short)((u + 0x7FFFu + ((u >> 16) & 1u)) >> 16);
}
__device__ inline float bf16_to_f(unsigned short h) {
    return __uint_as_float(((unsigned)h) << 16);
}
// pair word: hi in bits [15:0], lo in bits [31:16]
__device__ inline unsigned split2p(float x) {
    unsigned short hi = bf16_rne(x);
    unsigned short lo = bf16_rne(x - bf16_to_f(hi));
    return (unsigned)hi | ((unsigned)lo << 16);
}

// unpack 8 pair-words (2x uint4 regs) -> ah (8 hi bf16), al (8 lo bf16)
__device__ inline void unpair_r(uint4 q0, uint4 q1, bfrag& ah, bfrag& al) {
    union { uint32 u[4]; bfrag b; } H, L;
    H.u[0] = __builtin_amdgcn_perm(q0.y, q0.x, 0x05040100u);
    H.u[1] = __builtin_amdgcn_perm(q0.w, q0.z, 0x05040100u);
    H.u[2] = __builtin_amdgcn_perm(q1.y, q1.x, 0x05040100u);
    H.u[3] = __builtin_amdgcn_perm(q1.w, q1.z, 0x05040100u);
    L.u[0] = __builtin_amdgcn_perm(q0.y, q0.x, 0x07060302u);
    L.u[1] = __builtin_amdgcn_perm(q0.w, q0.z, 0x07060302u);
    L.u[2] = __builtin_amdgcn_perm(q1.y, q1.x, 0x07060302u);
    L.u[3] = __builtin_amdgcn_perm(q1.w, q1.z, 0x07060302u);
    ah = H.b;
    al = L.b;
}

// split 8 fp32 (2x uint4 regs, bit-cast) -> hi/lo bf16 fragments
__device__ inline void split8_r(uint4 q0, uint4 q1, bfrag& ah, bfrag& al) {
    float v[8] = {__uint_as_float(q0.x), __uint_as_float(q0.y), __uint_as_float(q0.z), __uint_as_float(q0.w),
                  __uint_as_float(q1.x), __uint_as_float(q1.y), __uint_as_float(q1.z), __uint_as_float(q1.w)};
    union { unsigned short us[8]; bfrag b; } H, L;
    #pragma unroll
    for (int i = 0; i < 8; i++) {
        unsigned pr = split2p(v[i]);
        H.us[i] = (unsigned short)pr;
        L.us[i] = (unsigned short)(pr >> 16);
    }
    ah = H.b;
    al = L.b;
}

// ---------------- compose Wc = W_pre @ W1 (fp32), pair-pack transposed; bc = b_pre @ W1 ----------------
// 4-lane k-split per output element (65536 threads, 256 blocks) + shfl reduce.
__global__ __launch_bounds__(256) void compose_w(const float* __restrict__ Wpre, const float* __restrict__ W1,
                                                 const float* __restrict__ bpre,
                                                 uint32* __restrict__ wcp, float* __restrict__ bc) {
    int gid = blockIdx.x * 256 + threadIdx.x;   // 65536 threads
    int i = gid >> 2;                           // output element 0..16383
    int kq = gid & 3;                           // k-quarter
    int n = i & 127, k = i >> 7;
    float acc = 0.f;
    #pragma unroll 8
    for (int m = kq * 32; m < kq * 32 + 32; m++)
        acc = fmaf(Wpre[k * 128 + m], W1[m * 128 + n], acc);
    acc += __shfl_xor(acc, 1);
    acc += __shfl_xor(acc, 2);
    if (kq == 0) {
        wcp[n * 128 + k] = split2p(acc);        // transposed pair-packed [n][k]
        if (i < 128) {
            float b = 0.f;
            #pragma unroll 8
            for (int m = 0; m < 128; m++)
                b = fmaf(bpre[m], W1[m * 128 + i], b);
            bc[i] = b;
        }
    }
}

// ---------------- degree from RAW edges + e32 compaction + csr sentinel + t' sentinel + W pack ----------------
__global__ __launch_bounds__(256) void deg_raw(const unsigned* __restrict__ raw, int* __restrict__ deg,
                                               unsigned* __restrict__ e32, unsigned short* __restrict__ csr16,
                                               float* __restrict__ t_c, int E, int Npad, int csrCap4, int nRows,
                                               const float* __restrict__ W2, const float* __restrict__ Wpost,
                                               uint32* __restrict__ w2_p, uint32* __restrict__ wpost_p) {
    __shared__ int smode;
    int gid = blockIdx.x * 256 + threadIdx.x;
    int gstride = gridDim.x * 256;
    int p0 = blockIdx.x * 1024;
    if (threadIdx.x < 64) {
        int p = p0 + threadIdx.x * 16;
        unsigned v = (p < E) ? raw[2 * p + 1] : 0u;
        unsigned long long any = __ballot(v != 0u);
        if (threadIdx.x == 0) smode = (any != 0ull) ? 1 : 0;
    }
    __syncthreads();
    int m = smode;
    // prefill csr with sentinel node index Npad (padded slots read the zero row)
    unsigned short sent = (unsigned short)Npad;
    ushort4 s4 = make_ushort4(sent, sent, sent, sent);
    for (int i = gid; i < csrCap4; i += gstride) ((ushort4*)csr16)[i] = s4;
    // zero the sentinel rows (row Npad..nRows-1 of each of the 8 chunks)
    int sentRows = nRows - Npad;
    int nSentF4 = 8 * sentRows * 4;   // float4 count
    for (int i = gid; i < nSentF4; i += gstride) {
        int chunk = i / (sentRows * 4);
        int rem = i % (sentRows * 4);
        ((float4*)(t_c + (size_t)chunk * nRows * 16 + (size_t)Npad * 16))[rem] = make_float4(0.f, 0.f, 0.f, 0.f);
    }
    // weight transpose + pair-pack (W2, Wpost)
    for (int i = gid; i < 22528; i += gstride) {
        const float* W; uint32* wp; int idx, ncols;
        if (i < 16384) { W = W2;    wp = w2_p;    idx = i;         ncols = 128; }
        else           { W = Wpost; wp = wpost_p; idx = i - 16384; ncols = 40;  }
        int n = idx >> 7, k = idx & 127;
        float v = (n < ncols) ? W[k * ncols + n] : 0.f;
        wp[idx] = split2p(v);
    }
    // degree count + edge compaction (src|dst<<16, both < 65536)
    int pend = min(p0 + 1024, E);
    for (int p = p0 + threadIdx.x; p < pend; p += 256) {
        int s, d;
        if (m) { s = (int)raw[p]; d = (int)raw[E + p]; }
        else   { s = (int)((const unsigned long long*)raw)[p]; d = (int)((const unsigned long long*)raw)[E + p]; }
        e32[p] = (unsigned)s | ((unsigned)d << 16);
        atomicAdd(&deg[d], 1);
    }
}

// ---- contention-free degree-bucket ranking (counting sort, hierarchical) ----
__global__ __launch_bounds__(256) void rank_block(const int* __restrict__ deg, float* __restrict__ dinv,
                                                  int* __restrict__ local_rank, int* __restrict__ hist_blk, int N) {
    __shared__ int h[256];
    int t = threadIdx.x;
    h[t] = 0;
    __syncthreads();
    int i = blockIdx.x * 256 + t;
    if (i < N) {
        int d = deg[i];
        dinv[i] = 1.0f / sqrtf((float)(d + 1));   // +1 self-loop
        int b = min(d, 255);
        local_rank[i] = atomicAdd(&h[b], 1);      // LDS atomic: intra-block only
    }
    __syncthreads();
    hist_blk[blockIdx.x * 256 + t] = h[t];
}

// B: scan blocks per bin, then dual LDS scan. ebase uses roundup4(deg) allocation.
__global__ __launch_bounds__(256) void scan_blocks(int* __restrict__ hist_blk, int* __restrict__ binbase,
                                                   int* __restrict__ ebase, int nblk) {
    int b = threadIdx.x;
    int sum = 0;
    int k = 0;
    for (; k + 8 <= nblk; k += 8) {
        int v[8];
        #pragma unroll
        for (int u = 0; u < 8; u++) v[u] = hist_blk[(k + u) * 256 + b];
        #pragma unroll
        for (int u = 0; u < 8; u++) { hist_blk[(k + u) * 256 + b] = sum; sum += v[u]; }
    }
    for (; k < nblk; k++) {
        int v = hist_blk[k * 256 + b];
        hist_blk[k * 256 + b] = sum;
        sum += v;
    }
    __shared__ int s[256], s2[256];
    int bp = (b + 3) & ~3;           // padded per-node edge allocation
    int c = sum, e = sum * bp;
    s[b] = c; s2[b] = e;
    __syncthreads();
    for (int off = 1; off < 256; off <<= 1) {
        int a0 = (b >= off) ? s[b - off] : 0;
        int a1 = (b >= off) ? s2[b - off] : 0;
        __syncthreads();
        s[b] += a0; s2[b] += a1;
        __syncthreads();
    }
    binbase[b] = s[b] - c;
    ebase[b] = s2[b] - e;
}

// C: emit sorted meta + rowbeg; edge allocations padded to multiples of 4 (8B-aligned ushort4)
__global__ __launch_bounds__(256) void emit_perm(const int* __restrict__ deg, const float* __restrict__ dinv,
                                                 const int* __restrict__ local_rank, const int* __restrict__ hist_blk,
                                                 const int* __restrict__ binbase, const int* __restrict__ ebase,
                                                 int* __restrict__ tailcur, int* __restrict__ rowbeg,
                                                 int* __restrict__ cursor, uint4* __restrict__ meta, int N) {
    int i = blockIdx.x * 256 + threadIdx.x;
    if (i >= N) return;
    int d = deg[i];
    int b = min(d, 255);
    int dp = (d + 3) & ~3;
    int rib = hist_blk[blockIdx.x * 256 + b] + local_rank[i];   // rank within bin
    int pos = binbase[b] + rib;
    int rb = (b < 255) ? (ebase[b] + rib * ((b + 3) & ~3)) : (ebase[255] + atomicAdd(tailcur, dp));
    rowbeg[i] = rb;
    cursor[i] = 0;
    meta[pos] = make_uint4((unsigned)rb, (unsigned)dp, __float_as_uint(dinv[i]), (unsigned)i);
}

// ---------------- CSR fill from compacted e32 ----------------
__global__ __launch_bounds__(256) void fill_csr_32(const unsigned* __restrict__ e32,
                                                   const int* __restrict__ rowbeg, int* __restrict__ cursor,
                                                   unsigned short* __restrict__ csr16, int E) {
    int e = blockIdx.x * 256 + threadIdx.x;
    if (e >= E) return;
    unsigned sd = e32[e];
    int s = (int)(sd & 0xFFFFu), d = (int)(sd >> 16);
    int pos = atomicAdd(&cursor[d], 1);
    csr16[rowbeg[d] + pos] = (unsigned short)s;
}

// ---------------- bf16x3 MFMA GEMM with W in LDS (pair-packed, padded) ----------------
// AFMT=0: A pair plane. AFMT=1: A fp32 (split in-register).
// EPI=0: Cf fp32 CHUNKED t'[chunk][row][16] = dinv[row]*(acc + bias[col]) (bias nullable).
// EPI=1: bias -> pair plane Pout.
template<int EPI, int AFMT>
__global__ __launch_bounds__(512) void gemm_lds(const void* __restrict__ Ap,
                                                const uint32* __restrict__ Wpair,
                                                const float* __restrict__ bias,
                                                const float* __restrict__ dinv,
                                                float* __restrict__ Cf,
                                                uint32* __restrict__ Pout,
                                                int nStrips, int N, int nRows) {
    __shared__ uint32 Wl[128 * 132];
    int tid = threadIdx.x;
    for (int i = tid; i < 16384; i += 512)
        Wl[(i >> 7) * 132 + (i & 127)] = Wpair[i];
    __syncthreads();

    int wave = tid >> 6;
    int lane = tid & 63;
    int l15 = lane & 15, lg = lane >> 4;
    int so = wave >> 1;
    int colbase = (wave & 1) * 64;
    size_t chunkStride = (size_t)nRows * 16;

    const int stride = gridDim.x * 4;
    for (int strip = blockIdx.x * 4 + so; strip < nStrips; strip += stride) {
        int arow = min(strip * 16 + l15, N - 1);
        uint4 cur[8];
        const uint4* p = (const uint4*)Ap + (size_t)arow * 32 + lg * 2;
        #pragma unroll
        for (int ks = 0; ks < 4; ks++) {
            cur[2 * ks]     = p[ks * 8];
            cur[2 * ks + 1] = p[ks * 8 + 1];
        }
        bfrag ah[4], al[4];
        #pragma unroll
        for (int ks = 0; ks < 4; ks++) {
            if (AFMT == 0) unpair_r(cur[2 * ks], cur[2 * ks + 1], ah[ks], al[ks]);
            else           split8_r(cur[2 * ks], cur[2 * ks + 1], ah[ks], al[ks]);
        }
        f32x4 acc[4];
        #pragma unroll
        for (int nt = 0; nt < 4; nt++) acc[nt] = (f32x4){0.f, 0.f, 0.f, 0.f};
        #pragma unroll
        for (int ks = 0; ks < 4; ks++) {
            #pragma unroll
            for (int nt = 0; nt < 4; nt++) {
                const uint32* wp = &Wl[(colbase + nt * 16 + l15) * 132 + ks * 32 + lg * 8];
                uint4 w0 = *(const uint4*)wp;
                uint4 w1 = *(const uint4*)(wp + 4);
                bfrag wh, wl_;
                unpair_r(w0, w1, wh, wl_);
                acc[nt] = __builtin_amdgcn_mfma_f32_16x16x32_bf16(ah[ks], wh, acc[nt], 0, 0, 0);
                acc[nt] = __builtin_amdgcn_mfma_f32_16x16x32_bf16(ah[ks], wl_, acc[nt], 0, 0, 0);
                acc[nt] = __builtin_amdgcn_mfma_f32_16x16x32_bf16(al[ks], wh, acc[nt], 0, 0, 0);
            }
        }
        int row0 = strip * 16;
        // C/D layout (m89-verified): col = lane&15, row = (lane>>4)*4 + reg
        if (EPI == 0) {
            float dv[4];
            #pragma unroll
            for (int r = 0; r < 4; r++) dv[r] = dinv[min(row0 + lg * 4 + r, N - 1)];
            #pragma unroll
            for (int nt = 0; nt < 4; nt++) {
                int col = colbase + nt * 16 + l15;
                float bv = bias ? bias[col] : 0.f;
                float* cbase = Cf + (size_t)(col >> 4) * chunkStride + (col & 15);
                #pragma unroll
                for (int r = 0; r < 4; r++)
                    cbase[(size_t)(row0 + lg * 4 + r) * 16] = (acc[nt][r] + bv) * dv[r];
            }
        } else {
            #pragma unroll
            for (int nt = 0; nt < 4; nt++) {
                int col = colbase + nt * 16 + l15;
                float bv = bias[col];
                #pragma unroll
                for (int r = 0; r < 4; r++)
                    Pout[(size_t)(row0 + lg * 4 + r) * D + col] = split2p(acc[nt][r] + bv);
            }
        }
    }
}

// ---------------- post GEMM (register-W, pair-packed source): out = h3 @ W_post + b ----------------
__global__ __launch_bounds__(256) void gemm_post(const uint32* __restrict__ P,
                                                 const uint32* __restrict__ Wpair,
                                                 const float* __restrict__ bias,
                                                 float* __restrict__ Cf,
                                                 int nStrips, int N, int outW) {
    int wave = threadIdx.x >> 6;
    int lane = threadIdx.x & 63;
    int l15 = lane & 15, lg = lane >> 4;

    bfrag wh[4][3], wl[4][3];
    #pragma unroll
    for (int ks = 0; ks < 4; ks++)
        #pragma unroll
        for (int nt = 0; nt < 3; nt++) {
            const uint32* wp = Wpair + (size_t)(nt * 16 + l15) * D + ks * 32 + lg * 8;
            uint4 w0 = *(const uint4*)wp;
            uint4 w1 = *(const uint4*)(wp + 4);
            unpair_r(w0, w1, wh[ks][nt], wl[ks][nt]);
        }

    const int stride = gridDim.x * 4;
    for (int strip = blockIdx.x * 4 + wave; strip < nStrips; strip += stride) {
        int arow = min(strip * 16 + l15, N - 1);
        bfrag ah[4], al[4];
        #pragma unroll
        for (int ks = 0; ks < 4; ks++) {
            const uint4* p = (const uint4*)P + (size_t)arow * 32 + lg * 2;
            unpair_r(p[ks * 8], p[ks * 8 + 1], ah[ks], al[ks]);
        }
        f32x4 acc[3];
        #pragma unroll
        for (int nt = 0; nt < 3; nt++) acc[nt] = (f32x4){0.f, 0.f, 0.f, 0.f};
        #pragma unroll
        for (int ks = 0; ks < 4; ks++)
            #pragma unroll
            for (int nt = 0; nt < 3; nt++) {
                acc[nt] = __builtin_amdgcn_mfma_f32_16x16x32_bf16(ah[ks], wh[ks][nt], acc[nt], 0, 0, 0);
                acc[nt] = __builtin_amdgcn_mfma_f32_16x16x32_bf16(ah[ks], wl[ks][nt], acc[nt], 0, 0, 0);
                acc[nt] = __builtin_amdgcn_mfma_f32_16x16x32_bf16(al[ks], wh[ks][nt], acc[nt], 0, 0, 0);
            }
        int row0 = strip * 16;
        #pragma unroll
        for (int nt = 0; nt < 3; nt++) {
            int col = nt * 16 + l15;
            #pragma unroll
            for (int r = 0; r < 4; r++) {
                int row = row0 + lg * 4 + r;
                if (row < N && col < outW)
                    Cf[(size_t)row * outW + col] = acc[nt][r] + bias[col];
            }
        }
    }
}

// ---------------- XCD-pinned chunked gather, degree-sorted, contiguous-way ushort4 CSR ----------------
__global__ __launch_bounds__(256) void gather_xcd(const unsigned short* __restrict__ csr16,
                                                  const uint4* __restrict__ meta,
                                                  const float* __restrict__ t_c, const float* __restrict__ bias,
                                                  uint32* __restrict__ Pout, int N, int nRows) {
    int chunk = blockIdx.x & 7;
    int k = (blockIdx.x >> 3) * 16 + (threadIdx.x >> 4);   // sorted position
    if (k >= N) return;
    uint4 m = meta[k];
    int beg = (int)m.x;
    int degp = (int)m.y;                                   // padded to multiple of 4
    float di = __uint_as_float(m.z);
    int node = (int)m.w;
    int w = (threadIdx.x >> 2) & 3;
    int c = threadIdx.x & 3;
    const float* tc = t_c + (size_t)chunk * nRows * 16 + c * 4;
    float4 a0 = make_float4(0.f, 0.f, 0.f, 0.f);
    float4 a1 = make_float4(0.f, 0.f, 0.f, 0.f);
    float4 a2 = make_float4(0.f, 0.f, 0.f, 0.f);
    float4 a3 = make_float4(0.f, 0.f, 0.f, 0.f);
    int end = beg + degp;
    for (int j = beg + 4 * w; j < end; j += 16) {
        ushort4 o = *(const ushort4*)(csr16 + j);          // 8B-aligned by construction
        float4 v0 = *(const float4*)(tc + ((size_t)o.x << 4));
        float4 v1 = *(const float4*)(tc + ((size_t)o.y << 4));
        float4 v2 = *(const float4*)(tc + ((size_t)o.z << 4));
        float4 v3 = *(const float4*)(tc + ((size_t)o.w << 4));
        a0.x += v0.x; a0.y += v0.y; a0.z += v0.z; a0.w += v0.w;
        a1.x += v1.x; a1.y += v1.y; a1.z += v1.z; a1.w += v1.w;
        a2.x += v2.x; a2.y += v2.y; a2.z += v2.z; a2.w += v2.w;
        a3.x += v3.x; a3.y += v3.y; a3.z += v3.z; a3.w += v3.w;
    }
    a0.x += a1.x; a0.y += a1.y; a0.z += a1.z; a0.w += a1.w;
    a2.x += a3.x; a2.y += a3.y; a2.z += a3.z; a2.w += a3.w;
    a0.x += a2.x; a0.y += a2.y; a0.z += a2.z; a0.w += a2.w;
    // combine 4 edge-ways (lane bits 2-3)
    a0.x += __shfl_xor(a0.x, 4); a0.y += __shfl_xor(a0.y, 4);
    a0.z += __shfl_xor(a0.z, 4); a0.w += __shfl_xor(a0.w, 4);
    a0.x += __shfl_xor(a0.x, 8); a0.y += __shfl_xor(a0.y, 8);
    a0.z += __shfl_xor(a0.z, 8); a0.w += __shfl_xor(a0.w, 8);
    if (w != 0) return;
    // t' pre-scaled by dinv: out = dinv[d]*(sum + t'[d]) + b
    float4 tv = *(const float4*)(tc + (size_t)node * 16);
    int col0 = chunk * 16 + c * 4;
    float4 b = *((const float4*)bias + (col0 >> 2));
    float4 r;
    r.x = fmaxf(fmaf(di, a0.x + tv.x, b.x), 0.f);
    r.y = fmaxf(fmaf(di, a0.y + tv.y, b.y), 0.f);
    r.z = fmaxf(fmaf(di, a0.z + tv.z, b.z), 0.f);
    r.w = fmaxf(fmaf(di, a0.w + tv.w, b.w), 0.f);
    uint4 p;
    p.x = split2p(r.x); p.y = split2p(r.y); p.z = split2p(r.z); p.w = split2p(r.w);
    *(uint4*)(Pout + (size_t)node * D + col0) = p;
}

extern "C" void kernel_launch(void* const* d_in, const int* in_sizes, int n_in,
                              void* d_out, int out_size, void* d_ws, size_t ws_size,
                              hipStream_t stream) {
    const float* x      = (const float*)d_in[0];
    const unsigned* edges = (const unsigned*)d_in[1];
    const float* W_pre  = (const float*)d_in[2];
    const float* b_pre  = (const float*)d_in[3];
    const float* W1     = (const float*)d_in[4];
    const float* b1     = (const float*)d_in[5];
    const float* W2     = (const float*)d_in[6];
    const float* b2     = (const float*)d_in[7];
    const float* W_post = (const float*)d_in[8];
    const float* b_post = (const float*)d_in[9];
    float* out = (float*)d_out;

    const int N = in_sizes[0] / D;        // 50000
    const int E = in_sizes[1] / 2;        // 800000
    const int nStrips = (N + 15) / 16;    // 3125
    const int Npad = nStrips * 16;
    const int nRows = Npad + 16;          // + sentinel rows (row Npad is the zero row)
    const int nBlk = (N + 255) / 256;     // 196
    const int csrCap = (E + 4 * N + 255) & ~255;   // padded csr capacity (shorts)

    // ---- workspace layout (persistent buffers) ----
    char* ws = (char*)d_ws;
    size_t off = 0;
    auto alloc = [&](size_t bytes) { void* p = ws + off; off += (bytes + 255) & ~(size_t)255; return p; };
    uint32* pairA = (uint32*)alloc((size_t)Npad * D * 4);   // pair plane A (h2)
    uint32* pairB = (uint32*)alloc((size_t)Npad * D * 4);   // pair plane B (h3)
    float*  bufT  = (float*)alloc((size_t)8 * nRows * 16 * 4);   // chunked pre-scaled t'[8][nRows][16]
    float*  dinv    = (float*)alloc((size_t)N * 4);
    int*    deg     = (int*)alloc((size_t)N * 4);
    int*    rowbeg  = (int*)alloc((size_t)N * 4);
    unsigned short* csr16 = (unsigned short*)alloc((size_t)csrCap * 2);
    uint4*  meta    = (uint4*)alloc((size_t)N * 16);
    unsigned* e32   = (unsigned*)alloc((size_t)E * 4);      // compacted edges (src|dst<<16)
    uint32* wc_p    = (uint32*)alloc(16384 * 4);   // pair-packed Wc = W_pre @ W1 (transposed)
    float*  bc      = (float*)alloc(128 * 4);      // b_pre @ W1
    uint32* w2_p    = (uint32*)alloc(16384 * 4);
    uint32* wpost_p = (uint32*)alloc(6144 * 4);

    // ---- prep-phase temporaries OVERLAY bufT (first ~1 MB; sentinel rows are beyond 3 MB) ----
    {
        char* t = (char*)bufT;
        size_t toff = 0;
        auto talloc = [&](size_t bytes) { void* p = t + toff; toff += (bytes + 255) & ~(size_t)255; return p; };
        int* cursor     = (int*)talloc((size_t)N * 4);
        int* local_rank = (int*)talloc((size_t)N * 4);
        int* hist_blk   = (int*)talloc((size_t)nBlk * 256 * 4); // ~200 KB
        int* mode2      = (int*)talloc(256);                    // [0]=unused, [1]=tail cursor
        int* binbase    = (int*)talloc(1024);
        int* ebase      = (int*)talloc(1024);
        int* tailcur = mode2 + 1;

        (void)hipMemsetAsync(mode2, 0, 8, stream);
        (void)hipMemsetAsync(deg, 0, (size_t)N * 4, stream);
        compose_w<<<256, 256, 0, stream>>>(W_pre, W1, b_pre, wc_p, bc);
        deg_raw<<<(E + 1023) / 1024, 256, 0, stream>>>(edges, deg, e32, csr16, bufT, E, Npad, csrCap / 4, nRows,
                                                       W2, W_post, w2_p, wpost_p);
        rank_block<<<nBlk, 256, 0, stream>>>(deg, dinv, local_rank, hist_blk, N);
        scan_blocks<<<1, 256, 0, stream>>>(hist_blk, binbase, ebase, nBlk);
        emit_perm<<<nBlk, 256, 0, stream>>>(deg, dinv, local_rank, hist_blk, binbase, ebase,
                                            tailcur, rowbeg, cursor, meta, N);
        fill_csr_32<<<(E + 255) / 256, 256, 0, stream>>>(e32, rowbeg, cursor, csr16, E);
    }

    const int nGatherBlocks = ((N + 15) / 16) * 8;   // 3125 node-blocks x 8 XCD chunks
    const int gemmGrid = 391;   // 1564 slots x 2 strips each; 2 blocks/CU fit (67.5 KB LDS)

    // conv1 (pre-MLP folded in): t1' = dinv*(x @ Wc + bc) (chunked) ; h2(pairA) = relu(dinv*(gather+self) + b1)
    gemm_lds<0, 1><<<gemmGrid, 512, 0, stream>>>(x, wc_p, bc, dinv, bufT, nullptr, nStrips, N, nRows);
    gather_xcd<<<nGatherBlocks, 256, 0, stream>>>(csr16, meta, bufT, b1, pairA, N, nRows);

    // conv2: t2' = dinv*(h2 @ W2) (chunked) ; h3(pairB) = relu(dinv*(gather+self) + b2)
    // NOTE: dispatched TWICE on purpose (idempotent) — measurement probe: Delta(total) = one gemm_lds cost.
    gemm_lds<0, 0><<<gemmGrid, 512, 0, stream>>>(pairA, w2_p, nullptr, dinv, bufT, nullptr, nStrips, N, nRows);
    gemm_lds<0, 0><<<gemmGrid, 512, 0, stream>>>(pairA, w2_p, nullptr, dinv, bufT, nullptr, nStrips, N, nRows);
    gather_xcd<<<nGatherBlocks, 256, 0, stream>>>(csr16, meta, bufT, b2, pairB, N, nRows);

    // post MLP: out = h3 @ W_post + b_post  (40 cols, padded to 48)
    gemm_post<<<256, 256, 0, stream>>>(pairB, wpost_p, b_post, out, nStrips, N, 40);
}

// Round 18
// 257.077 us; speedup vs baseline: 1.0833x; 1.0833x over previous
//
#include <hip/hip_runtime.h>

#define D 128

typedef short bfrag __attribute__((ext_vector_type(8)));      // 8 bf16 = 4 VGPRs
typedef float f32x4 __attribute__((ext_vector_type(4)));
typedef unsigned uint32;

// ---------------- bf16 split helpers ----------------
__device__ inline unsigned short bf16_rne(float x) {
    unsigned u = __float_as_uint(x);
    return (unsigned short)((u + 0x7FFFu + ((u >> 16) & 1u)) >> 16);
}
__device__ inline float bf16_to_f(unsigned short h) {
    return __uint_as_float(((unsigned)h) << 16);
}
// pair word: hi in bits [15:0], lo in bits [31:16]
__device__ inline unsigned split2p(float x) {
    unsigned short hi = bf16_rne(x);
    unsigned short lo = bf16_rne(x - bf16_to_f(hi));
    return (unsigned)hi | ((unsigned)lo << 16);
}

// unpack 8 pair-words (2x uint4 regs) -> ah (8 hi bf16), al (8 lo bf16)
__device__ inline void unpair_r(uint4 q0, uint4 q1, bfrag& ah, bfrag& al) {
    union { uint32 u[4]; bfrag b; } H, L;
    H.u[0] = __builtin_amdgcn_perm(q0.y, q0.x, 0x05040100u);
    H.u[1] = __builtin_amdgcn_perm(q0.w, q0.z, 0x05040100u);
    H.u[2] = __builtin_amdgcn_perm(q1.y, q1.x, 0x05040100u);
    H.u[3] = __builtin_amdgcn_perm(q1.w, q1.z, 0x05040100u);
    L.u[0] = __builtin_amdgcn_perm(q0.y, q0.x, 0x07060302u);
    L.u[1] = __builtin_amdgcn_perm(q0.w, q0.z, 0x07060302u);
    L.u[2] = __builtin_amdgcn_perm(q1.y, q1.x, 0x07060302u);
    L.u[3] = __builtin_amdgcn_perm(q1.w, q1.z, 0x07060302u);
    ah = H.b;
    al = L.b;
}

// split 8 fp32 (2x uint4 regs, bit-cast) -> hi/lo bf16 fragments
__device__ inline void split8_r(uint4 q0, uint4 q1, bfrag& ah, bfrag& al) {
    float v[8] = {__uint_as_float(q0.x), __uint_as_float(q0.y), __uint_as_float(q0.z), __uint_as_float(q0.w),
                  __uint_as_float(q1.x), __uint_as_float(q1.y), __uint_as_float(q1.z), __uint_as_float(q1.w)};
    union { unsigned short us[8]; bfrag b; } H, L;
    #pragma unroll
    for (int i = 0; i < 8; i++) {
        unsigned pr = split2p(v[i]);
        H.us[i] = (unsigned short)pr;
        L.us[i] = (unsigned short)(pr >> 16);
    }
    ah = H.b;
    al = L.b;
}

// ---------------- compose Wc = W_pre @ W1 (fp32), pair-pack transposed; bc = b_pre @ W1 ----------------
__global__ __launch_bounds__(256) void compose_w(const float* __restrict__ Wpre, const float* __restrict__ W1,
                                                 const float* __restrict__ bpre,
                                                 uint32* __restrict__ wcp, float* __restrict__ bc) {
    int gid = blockIdx.x * 256 + threadIdx.x;   // 65536 threads
    int i = gid >> 2;                           // output element 0..16383
    int kq = gid & 3;                           // k-quarter
    int n = i & 127, k = i >> 7;
    float acc = 0.f;
    #pragma unroll 8
    for (int m = kq * 32; m < kq * 32 + 32; m++)
        acc = fmaf(Wpre[k * 128 + m], W1[m * 128 + n], acc);
    acc += __shfl_xor(acc, 1);
    acc += __shfl_xor(acc, 2);
    if (kq == 0) {
        wcp[n * 128 + k] = split2p(acc);        // transposed pair-packed [n][k]
        if (i < 128) {
            float b = 0.f;
            #pragma unroll 8
            for (int m = 0; m < 128; m++)
                b = fmaf(bpre[m], W1[m * 128 + i], b);
            bc[i] = b;
        }
    }
}

// ---------------- atomic-free prep: e32 compaction + sentinels + W pack + zero deg ----------------
__global__ __launch_bounds__(256) void compact_misc(const unsigned* __restrict__ raw, unsigned* __restrict__ e32,
                                                    int* __restrict__ deg, int* __restrict__ tailcur,
                                                    unsigned short* __restrict__ csr16, float* __restrict__ t_c,
                                                    int E, int N, int Npad, int csrCap4, int nRows,
                                                    const float* __restrict__ W2, const float* __restrict__ Wpost,
                                                    uint32* __restrict__ w2_p, uint32* __restrict__ wpost_p) {
    __shared__ int smode;
    int gid = blockIdx.x * 256 + threadIdx.x;
    int gstride = gridDim.x * 256;
    int p0 = blockIdx.x * 1024;
    if (threadIdx.x < 64) {
        int p = p0 + threadIdx.x * 16;
        unsigned v = (p < E) ? raw[2 * p + 1] : 0u;
        unsigned long long any = __ballot(v != 0u);
        if (threadIdx.x == 0) smode = (any != 0ull) ? 1 : 0;
    }
    __syncthreads();
    int m = smode;
    if (gid == 0) *tailcur = 0;
    for (int i = gid; i < N; i += gstride) deg[i] = 0;
    // prefill csr with sentinel node index Npad (padded slots read the zero row)
    unsigned short sent = (unsigned short)Npad;
    ushort4 s4 = make_ushort4(sent, sent, sent, sent);
    for (int i = gid; i < csrCap4; i += gstride) ((ushort4*)csr16)[i] = s4;
    // zero the sentinel rows (row Npad..nRows-1 of each of the 8 chunks)
    int sentRows = nRows - Npad;
    int nSentF4 = 8 * sentRows * 4;
    for (int i = gid; i < nSentF4; i += gstride) {
        int chunk = i / (sentRows * 4);
        int rem = i % (sentRows * 4);
        ((float4*)(t_c + (size_t)chunk * nRows * 16 + (size_t)Npad * 16))[rem] = make_float4(0.f, 0.f, 0.f, 0.f);
    }
    // weight transpose + pair-pack (W2, Wpost)
    for (int i = gid; i < 22528; i += gstride) {
        const float* W; uint32* wp; int idx, ncols;
        if (i < 16384) { W = W2;    wp = w2_p;    idx = i;         ncols = 128; }
        else           { W = Wpost; wp = wpost_p; idx = i - 16384; ncols = 40;  }
        int n = idx >> 7, k = idx & 127;
        float v = (n < ncols) ? W[k * ncols + n] : 0.f;
        wp[idx] = split2p(v);
    }
    // edge compaction (src|dst<<16, both < 65536), no atomics
    int pend = min(p0 + 1024, E);
    for (int p = p0 + threadIdx.x; p < pend; p += 256) {
        int s, d;
        if (m) { s = (int)raw[p]; d = (int)raw[E + p]; }
        else   { s = (int)((const unsigned long long*)raw)[p]; d = (int)((const unsigned long long*)raw)[E + p]; }
        e32[p] = (unsigned)s | ((unsigned)d << 16);
    }
}

// ---------------- XCD-local degree count: chunk owns node-id range -> deg lines live in ONE L2 ----------------
__global__ __launch_bounds__(256) void deg_count_xcd(const unsigned* __restrict__ e32, int* __restrict__ deg,
                                                     int E, float scale) {
    int chunk = blockIdx.x & 7;
    int e = (blockIdx.x >> 3) * 256 + threadIdx.x;
    if (e >= E) return;
    int d = (int)(e32[e] >> 16);
    int c = min((int)((float)d * scale), 7);
    if (c != chunk) return;
    atomicAdd(&deg[d], 1);
}

// ---- contention-free degree-bucket ranking (counting sort, hierarchical) ----
__global__ __launch_bounds__(256) void rank_block(const int* __restrict__ deg, float* __restrict__ dinv,
                                                  int* __restrict__ local_rank, int* __restrict__ hist_blk, int N) {
    __shared__ int h[256];
    int t = threadIdx.x;
    h[t] = 0;
    __syncthreads();
    int i = blockIdx.x * 256 + t;
    if (i < N) {
        int d = deg[i];
        dinv[i] = 1.0f / sqrtf((float)(d + 1));   // +1 self-loop
        int b = min(d, 255);
        local_rank[i] = atomicAdd(&h[b], 1);      // LDS atomic: intra-block only
    }
    __syncthreads();
    hist_blk[blockIdx.x * 256 + t] = h[t];
}

// B: scan blocks per bin, then dual LDS scan. ebase uses roundup4(deg) allocation.
__global__ __launch_bounds__(256) void scan_blocks(int* __restrict__ hist_blk, int* __restrict__ binbase,
                                                   int* __restrict__ ebase, int nblk) {
    int b = threadIdx.x;
    int sum = 0;
    int k = 0;
    for (; k + 8 <= nblk; k += 8) {
        int v[8];
        #pragma unroll
        for (int u = 0; u < 8; u++) v[u] = hist_blk[(k + u) * 256 + b];
        #pragma unroll
        for (int u = 0; u < 8; u++) { hist_blk[(k + u) * 256 + b] = sum; sum += v[u]; }
    }
    for (; k < nblk; k++) {
        int v = hist_blk[k * 256 + b];
        hist_blk[k * 256 + b] = sum;
        sum += v;
    }
    __shared__ int s[256], s2[256];
    int bp = (b + 3) & ~3;           // padded per-node edge allocation
    int c = sum, e = sum * bp;
    s[b] = c; s2[b] = e;
    __syncthreads();
    for (int off = 1; off < 256; off <<= 1) {
        int a0 = (b >= off) ? s[b - off] : 0;
        int a1 = (b >= off) ? s2[b - off] : 0;
        __syncthreads();
        s[b] += a0; s2[b] += a1;
        __syncthreads();
    }
    binbase[b] = s[b] - c;
    ebase[b] = s2[b] - e;
}

// C: emit sorted meta + rowbeg; edge allocations padded to multiples of 4 (8B-aligned ushort4)
__global__ __launch_bounds__(256) void emit_perm(const int* __restrict__ deg, const float* __restrict__ dinv,
                                                 const int* __restrict__ local_rank, const int* __restrict__ hist_blk,
                                                 const int* __restrict__ binbase, const int* __restrict__ ebase,
                                                 int* __restrict__ tailcur, int* __restrict__ rowbeg,
                                                 int* __restrict__ cursor, uint4* __restrict__ meta, int N) {
    int i = blockIdx.x * 256 + threadIdx.x;
    if (i >= N) return;
    int d = deg[i];
    int b = min(d, 255);
    int dp = (d + 3) & ~3;
    int rib = hist_blk[blockIdx.x * 256 + b] + local_rank[i];   // rank within bin
    int pos = binbase[b] + rib;
    int rb = (b < 255) ? (ebase[b] + rib * ((b + 3) & ~3)) : (ebase[255] + atomicAdd(tailcur, dp));
    rowbeg[i] = rb;
    cursor[i] = 0;
    meta[pos] = make_uint4((unsigned)rb, (unsigned)dp, __float_as_uint(dinv[i]), (unsigned)i);
}

// ---------------- XCD-local CSR fill: chunk owns csr-position range -> csr/cursor lines in ONE L2 ----------------
__global__ __launch_bounds__(256) void fill_csr_xcd(const unsigned* __restrict__ e32, const int* __restrict__ rowbeg,
                                                    int* __restrict__ cursor, unsigned short* __restrict__ csr16,
                                                    int E, float scale) {
    int chunk = blockIdx.x & 7;
    int e = (blockIdx.x >> 3) * 256 + threadIdx.x;
    if (e >= E) return;
    unsigned sd = e32[e];
    int d = (int)(sd >> 16);
    int rb = rowbeg[d];
    int c = min((int)((float)rb * scale), 7);
    if (c != chunk) return;
    int pos = atomicAdd(&cursor[d], 1);
    csr16[rb + pos] = (unsigned short)(sd & 0xFFFFu);
}

// ---------------- bf16x3 MFMA GEMM with W in LDS (pair-packed, padded) ----------------
// AFMT=0: A pair plane. AFMT=1: A fp32 (split in-register).
// EPI=0: Cf fp32 CHUNKED t'[chunk][row][16] = dinv[row]*(acc + bias[col]) (bias nullable).
// EPI=1: bias -> pair plane Pout.
template<int EPI, int AFMT>
__global__ __launch_bounds__(512) void gemm_lds(const void* __restrict__ Ap,
                                                const uint32* __restrict__ Wpair,
                                                const float* __restrict__ bias,
                                                const float* __restrict__ dinv,
                                                float* __restrict__ Cf,
                                                uint32* __restrict__ Pout,
                                                int nStrips, int N, int nRows) {
    __shared__ uint32 Wl[128 * 132];
    int tid = threadIdx.x;
    for (int i = tid; i < 16384; i += 512)
        Wl[(i >> 7) * 132 + (i & 127)] = Wpair[i];
    __syncthreads();

    int wave = tid >> 6;
    int lane = tid & 63;
    int l15 = lane & 15, lg = lane >> 4;
    int so = wave >> 1;
    int colbase = (wave & 1) * 64;
    size_t chunkStride = (size_t)nRows * 16;

    const int stride = gridDim.x * 4;
    for (int strip = blockIdx.x * 4 + so; strip < nStrips; strip += stride) {
        int arow = min(strip * 16 + l15, N - 1);
        uint4 cur[8];
        const uint4* p = (const uint4*)Ap + (size_t)arow * 32 + lg * 2;
        #pragma unroll
        for (int ks = 0; ks < 4; ks++) {
            cur[2 * ks]     = p[ks * 8];
            cur[2 * ks + 1] = p[ks * 8 + 1];
        }
        bfrag ah[4], al[4];
        #pragma unroll
        for (int ks = 0; ks < 4; ks++) {
            if (AFMT == 0) unpair_r(cur[2 * ks], cur[2 * ks + 1], ah[ks], al[ks]);
            else           split8_r(cur[2 * ks], cur[2 * ks + 1], ah[ks], al[ks]);
        }
        f32x4 acc[4];
        #pragma unroll
        for (int nt = 0; nt < 4; nt++) acc[nt] = (f32x4){0.f, 0.f, 0.f, 0.f};
        #pragma unroll
        for (int ks = 0; ks < 4; ks++) {
            #pragma unroll
            for (int nt = 0; nt < 4; nt++) {
                const uint32* wp = &Wl[(colbase + nt * 16 + l15) * 132 + ks * 32 + lg * 8];
                uint4 w0 = *(const uint4*)wp;
                uint4 w1 = *(const uint4*)(wp + 4);
                bfrag wh, wl_;
                unpair_r(w0, w1, wh, wl_);
                acc[nt] = __builtin_amdgcn_mfma_f32_16x16x32_bf16(ah[ks], wh, acc[nt], 0, 0, 0);
                acc[nt] = __builtin_amdgcn_mfma_f32_16x16x32_bf16(ah[ks], wl_, acc[nt], 0, 0, 0);
                acc[nt] = __builtin_amdgcn_mfma_f32_16x16x32_bf16(al[ks], wh, acc[nt], 0, 0, 0);
            }
        }
        int row0 = strip * 16;
        // C/D layout (m89-verified): col = lane&15, row = (lane>>4)*4 + reg
        if (EPI == 0) {
            float dv[4];
            #pragma unroll
            for (int r = 0; r < 4; r++) dv[r] = dinv[min(row0 + lg * 4 + r, N - 1)];
            #pragma unroll
            for (int nt = 0; nt < 4; nt++) {
                int col = colbase + nt * 16 + l15;
                float bv = bias ? bias[col] : 0.f;
                float* cbase = Cf + (size_t)(col >> 4) * chunkStride + (col & 15);
                #pragma unroll
                for (int r = 0; r < 4; r++)
                    cbase[(size_t)(row0 + lg * 4 + r) * 16] = (acc[nt][r] + bv) * dv[r];
            }
        } else {
            #pragma unroll
            for (int nt = 0; nt < 4; nt++) {
                int col = colbase + nt * 16 + l15;
                float bv = bias[col];
                #pragma unroll
                for (int r = 0; r < 4; r++)
                    Pout[(size_t)(row0 + lg * 4 + r) * D + col] = split2p(acc[nt][r] + bv);
            }
        }
    }
}

// ---------------- post GEMM (register-W, pair-packed source): out = h3 @ W_post + b ----------------
__global__ __launch_bounds__(256) void gemm_post(const uint32* __restrict__ P,
                                                 const uint32* __restrict__ Wpair,
                                                 const float* __restrict__ bias,
                                                 float* __restrict__ Cf,
                                                 int nStrips, int N, int outW) {
    int wave = threadIdx.x >> 6;
    int lane = threadIdx.x & 63;
    int l15 = lane & 15, lg = lane >> 4;

    bfrag wh[4][3], wl[4][3];
    #pragma unroll
    for (int ks = 0; ks < 4; ks++)
        #pragma unroll
        for (int nt = 0; nt < 3; nt++) {
            const uint32* wp = Wpair + (size_t)(nt * 16 + l15) * D + ks * 32 + lg * 8;
            uint4 w0 = *(const uint4*)wp;
            uint4 w1 = *(const uint4*)(wp + 4);
            unpair_r(w0, w1, wh[ks][nt], wl[ks][nt]);
        }

    const int stride = gridDim.x * 4;
    for (int strip = blockIdx.x * 4 + wave; strip < nStrips; strip += stride) {
        int arow = min(strip * 16 + l15, N - 1);
        bfrag ah[4], al[4];
        #pragma unroll
        for (int ks = 0; ks < 4; ks++) {
            const uint4* p = (const uint4*)P + (size_t)arow * 32 + lg * 2;
            unpair_r(p[ks * 8], p[ks * 8 + 1], ah[ks], al[ks]);
        }
        f32x4 acc[3];
        #pragma unroll
        for (int nt = 0; nt < 3; nt++) acc[nt] = (f32x4){0.f, 0.f, 0.f, 0.f};
        #pragma unroll
        for (int ks = 0; ks < 4; ks++)
            #pragma unroll
            for (int nt = 0; nt < 3; nt++) {
                acc[nt] = __builtin_amdgcn_mfma_f32_16x16x32_bf16(ah[ks], wh[ks][nt], acc[nt], 0, 0, 0);
                acc[nt] = __builtin_amdgcn_mfma_f32_16x16x32_bf16(ah[ks], wl[ks][nt], acc[nt], 0, 0, 0);
                acc[nt] = __builtin_amdgcn_mfma_f32_16x16x32_bf16(al[ks], wh[ks][nt], acc[nt], 0, 0, 0);
            }
        int row0 = strip * 16;
        #pragma unroll
        for (int nt = 0; nt < 3; nt++) {
            int col = nt * 16 + l15;
            #pragma unroll
            for (int r = 0; r < 4; r++) {
                int row = row0 + lg * 4 + r;
                if (row < N && col < outW)
                    Cf[(size_t)row * outW + col] = acc[nt][r] + bias[col];
            }
        }
    }
}

// ---------------- XCD-pinned chunked gather, degree-sorted, contiguous-way ushort4 CSR ----------------
__global__ __launch_bounds__(256) void gather_xcd(const unsigned short* __restrict__ csr16,
                                                  const uint4* __restrict__ meta,
                                                  const float* __restrict__ t_c, const float* __restrict__ bias,
                                                  uint32* __restrict__ Pout, int N, int nRows) {
    int chunk = blockIdx.x & 7;
    int k = (blockIdx.x >> 3) * 16 + (threadIdx.x >> 4);   // sorted position
    if (k >= N) return;
    uint4 m = meta[k];
    int beg = (int)m.x;
    int degp = (int)m.y;                                   // padded to multiple of 4
    float di = __uint_as_float(m.z);
    int node = (int)m.w;
    int w = (threadIdx.x >> 2) & 3;
    int c = threadIdx.x & 3;
    const float* tc = t_c + (size_t)chunk * nRows * 16 + c * 4;
    float4 a0 = make_float4(0.f, 0.f, 0.f, 0.f);
    float4 a1 = make_float4(0.f, 0.f, 0.f, 0.f);
    float4 a2 = make_float4(0.f, 0.f, 0.f, 0.f);
    float4 a3 = make_float4(0.f, 0.f, 0.f, 0.f);
    int end = beg + degp;
    for (int j = beg + 4 * w; j < end; j += 16) {
        ushort4 o = *(const ushort4*)(csr16 + j);          // 8B-aligned by construction
        float4 v0 = *(const float4*)(tc + ((size_t)o.x << 4));
        float4 v1 = *(const float4*)(tc + ((size_t)o.y << 4));
        float4 v2 = *(const float4*)(tc + ((size_t)o.z << 4));
        float4 v3 = *(const float4*)(tc + ((size_t)o.w << 4));
        a0.x += v0.x; a0.y += v0.y; a0.z += v0.z; a0.w += v0.w;
        a1.x += v1.x; a1.y += v1.y; a1.z += v1.z; a1.w += v1.w;
        a2.x += v2.x; a2.y += v2.y; a2.z += v2.z; a2.w += v2.w;
        a3.x += v3.x; a3.y += v3.y; a3.z += v3.z; a3.w += v3.w;
    }
    a0.x += a1.x; a0.y += a1.y; a0.z += a1.z; a0.w += a1.w;
    a2.x += a3.x; a2.y += a3.y; a2.z += a3.z; a2.w += a3.w;
    a0.x += a2.x; a0.y += a2.y; a0.z += a2.z; a0.w += a2.w;
    // combine 4 edge-ways (lane bits 2-3)
    a0.x += __shfl_xor(a0.x, 4); a0.y += __shfl_xor(a0.y, 4);
    a0.z += __shfl_xor(a0.z, 4); a0.w += __shfl_xor(a0.w, 4);
    a0.x += __shfl_xor(a0.x, 8); a0.y += __shfl_xor(a0.y, 8);
    a0.z += __shfl_xor(a0.z, 8); a0.w += __shfl_xor(a0.w, 8);
    if (w != 0) return;
    // t' pre-scaled by dinv: out = dinv[d]*(sum + t'[d]) + b
    float4 tv = *(const float4*)(tc + (size_t)node * 16);
    int col0 = chunk * 16 + c * 4;
    float4 b = *((const float4*)bias + (col0 >> 2));
    float4 r;
    r.x = fmaxf(fmaf(di, a0.x + tv.x, b.x), 0.f);
    r.y = fmaxf(fmaf(di, a0.y + tv.y, b.y), 0.f);
    r.z = fmaxf(fmaf(di, a0.z + tv.z, b.z), 0.f);
    r.w = fmaxf(fmaf(di, a0.w + tv.w, b.w), 0.f);
    uint4 p;
    p.x = split2p(r.x); p.y = split2p(r.y); p.z = split2p(r.z); p.w = split2p(r.w);
    *(uint4*)(Pout + (size_t)node * D + col0) = p;
}

extern "C" void kernel_launch(void* const* d_in, const int* in_sizes, int n_in,
                              void* d_out, int out_size, void* d_ws, size_t ws_size,
                              hipStream_t stream) {
    const float* x      = (const float*)d_in[0];
    const unsigned* edges = (const unsigned*)d_in[1];
    const float* W_pre  = (const float*)d_in[2];
    const float* b_pre  = (const float*)d_in[3];
    const float* W1     = (const float*)d_in[4];
    const float* b1     = (const float*)d_in[5];
    const float* W2     = (const float*)d_in[6];
    const float* b2     = (const float*)d_in[7];
    const float* W_post = (const float*)d_in[8];
    const float* b_post = (const float*)d_in[9];
    float* out = (float*)d_out;

    const int N = in_sizes[0] / D;        // 50000
    const int E = in_sizes[1] / 2;        // 800000
    const int nStrips = (N + 15) / 16;    // 3125
    const int Npad = nStrips * 16;
    const int nRows = Npad + 16;          // + sentinel rows (row Npad is the zero row)
    const int nBlk = (N + 255) / 256;     // 196
    const int csrCap = (E + 4 * N + 255) & ~255;   // padded csr capacity (shorts)

    // ---- workspace layout (persistent buffers) ----
    char* ws = (char*)d_ws;
    size_t off = 0;
    auto alloc = [&](size_t bytes) { void* p = ws + off; off += (bytes + 255) & ~(size_t)255; return p; };
    uint32* pairA = (uint32*)alloc((size_t)Npad * D * 4);   // pair plane A (h2)
    uint32* pairB = (uint32*)alloc((size_t)Npad * D * 4);   // pair plane B (h3)
    float*  bufT  = (float*)alloc((size_t)8 * nRows * 16 * 4);   // chunked pre-scaled t'[8][nRows][16]
    float*  dinv    = (float*)alloc((size_t)N * 4);
    int*    deg     = (int*)alloc((size_t)N * 4);
    int*    rowbeg  = (int*)alloc((size_t)N * 4);
    unsigned short* csr16 = (unsigned short*)alloc((size_t)csrCap * 2);
    uint4*  meta    = (uint4*)alloc((size_t)N * 16);
    unsigned* e32   = (unsigned*)alloc((size_t)E * 4);      // compacted edges (src|dst<<16)
    uint32* wc_p    = (uint32*)alloc(16384 * 4);   // pair-packed Wc = W_pre @ W1 (transposed)
    float*  bc      = (float*)alloc(128 * 4);      // b_pre @ W1
    uint32* w2_p    = (uint32*)alloc(16384 * 4);
    uint32* wpost_p = (uint32*)alloc(6144 * 4);

    // ---- prep-phase temporaries OVERLAY bufT (first ~1 MB; sentinel rows are beyond 3 MB) ----
    {
        char* t = (char*)bufT;
        size_t toff = 0;
        auto talloc = [&](size_t bytes) { void* p = t + toff; toff += (bytes + 255) & ~(size_t)255; return p; };
        int* cursor     = (int*)talloc((size_t)N * 4);
        int* local_rank = (int*)talloc((size_t)N * 4);
        int* hist_blk   = (int*)talloc((size_t)nBlk * 256 * 4); // ~200 KB
        int* mode2      = (int*)talloc(256);                    // [1]=tail cursor
        int* binbase    = (int*)talloc(1024);
        int* ebase      = (int*)talloc(1024);
        int* tailcur = mode2 + 1;

        const float scaleDeg  = 8.0f / (float)N;
        const float scaleFill = 8.0f / (float)csrCap;
        const int nEdgeBlk8 = ((E + 255) / 256) * 8;

        compose_w<<<256, 256, 0, stream>>>(W_pre, W1, b_pre, wc_p, bc);
        compact_misc<<<(E + 1023) / 1024, 256, 0, stream>>>(edges, e32, deg, tailcur, csr16, bufT,
                                                            E, N, Npad, csrCap / 4, nRows,
                                                            W2, W_post, w2_p, wpost_p);
        deg_count_xcd<<<nEdgeBlk8, 256, 0, stream>>>(e32, deg, E, scaleDeg);
        rank_block<<<nBlk, 256, 0, stream>>>(deg, dinv, local_rank, hist_blk, N);
        scan_blocks<<<1, 256, 0, stream>>>(hist_blk, binbase, ebase, nBlk);
        emit_perm<<<nBlk, 256, 0, stream>>>(deg, dinv, local_rank, hist_blk, binbase, ebase,
                                            tailcur, rowbeg, cursor, meta, N);
        fill_csr_xcd<<<nEdgeBlk8, 256, 0, stream>>>(e32, rowbeg, cursor, csr16, E, scaleFill);
    }

    const int nGatherBlocks = ((N + 15) / 16) * 8;   // 3125 node-blocks x 8 XCD chunks
    const int gemmGrid = 391;   // 1564 slots x 2 strips each; 2 blocks/CU fit (67.5 KB LDS)

    // conv1 (pre-MLP folded in): t1' = dinv*(x @ Wc + bc) (chunked) ; h2(pairA) = relu(dinv*(gather+self) + b1)
    gemm_lds<0, 1><<<gemmGrid, 512, 0, stream>>>(x, wc_p, bc, dinv, bufT, nullptr, nStrips, N, nRows);
    gather_xcd<<<nGatherBlocks, 256, 0, stream>>>(csr16, meta, bufT, b1, pairA, N, nRows);

    // conv2: t2' = dinv*(h2 @ W2) (chunked) ; h3(pairB) = relu(dinv*(gather+self) + b2)
    gemm_lds<0, 0><<<gemmGrid, 512, 0, stream>>>(pairA, w2_p, nullptr, dinv, bufT, nullptr, nStrips, N, nRows);
    gather_xcd<<<nGatherBlocks, 256, 0, stream>>>(csr16, meta, bufT, b2, pairB, N, nRows);

    // post MLP: out = h3 @ W_post + b_post  (40 cols, padded to 48)
    gemm_post<<<256, 256, 0, stream>>>(pairB, wpost_p, b_post, out, nStrips, N, 40);
}